// Round 3
// baseline (868.728 us; speedup 1.0000x reference)
//
#include <hip/hip_runtime.h>

#define SCALE 0.17677669529663687f

typedef __attribute__((ext_vector_type(8))) short short8;
typedef __attribute__((ext_vector_type(4))) float f32x4;
typedef __attribute__((ext_vector_type(4))) _Float16 half4;

__device__ __forceinline__ f32x4 MFMA32(short8 a, short8 b, f32x4 c) {
  return __builtin_amdgcn_mfma_f32_16x16x32_bf16(a, b, c, 0, 0, 0);
}

__device__ __forceinline__ f32x4 MFMA16(half4 a, half4 b, f32x4 c) {
  return __builtin_amdgcn_mfma_f32_16x16x16f16(a, b, c, 0, 0, 0);
}

__device__ __forceinline__ unsigned short f2bf(float f) {
  unsigned u = __float_as_uint(f);
  u += 0x7fffu + ((u >> 16) & 1u);
  return (unsigned short)(u >> 16);
}

__device__ __forceinline__ unsigned long long pack4(float a, float b, float c, float d) {
  unsigned lo = (unsigned)f2bf(a) | ((unsigned)f2bf(b) << 16);
  unsigned hi = (unsigned)f2bf(c) | ((unsigned)f2bf(d) << 16);
  return (unsigned long long)lo | ((unsigned long long)hi << 32);
}

// ---- Prologue: weights fp32->bf16 + rpe gather, one kernel.
// idx < 196608: qkv_wb ; < 262144: proj_wb ; < 294912: rpe[h][i][j]
__global__ void prep_kernel(const float* __restrict__ qkv_w,
                            const float* __restrict__ proj_w,
                            const float* __restrict__ table,
                            const int* __restrict__ rel,
                            unsigned short* __restrict__ qkv_wb,
                            unsigned short* __restrict__ proj_wb,
                            float* __restrict__ rpe) {
  int idx = blockIdx.x * 256 + threadIdx.x;   // 1152 * 256 = 294912 exact
  if (idx < 196608) {
    qkv_wb[idx] = f2bf(qkv_w[idx]);
  } else if (idx < 262144) {
    int p = idx - 196608;
    proj_wb[p] = f2bf(proj_w[p]);
  } else {
    int t = idx - 262144;                     // 0..32767
    int h = t >> 12, ij = t & 4095;
    rpe[t] = table[rel[ij] * 8 + h];
  }
}

// ---- Main fused kernel: one block per window, 8 waves = 8 heads.
// All attention intermediates (q,k,v,S,P,O) live in REGISTERS via transposed
// MFMA chaining; LDS holds only x (bf16, [64][264]) reused later for O_all.
__global__ __launch_bounds__(512, 4)
void win_attn_kernel(const float* __restrict__ x,
                     const float* __restrict__ mask,
                     const unsigned short* __restrict__ qkv_wb,
                     const float* __restrict__ qkv_b,
                     const unsigned short* __restrict__ proj_wb,
                     const float* __restrict__ proj_b,
                     const float* __restrict__ rpe,
                     float* __restrict__ out) {
  __shared__ unsigned short lds[64 * 264];
  const int bid  = blockIdx.x;
  const int tid  = threadIdx.x;
  const int w    = tid >> 6;     // wave = head
  const int lane = tid & 63;
  const int lr   = lane & 15;
  const int lg   = lane >> 4;
  const f32x4 z4 = {0.f, 0.f, 0.f, 0.f};

  // ---- Phase 1: stage x -> LDS bf16 [64][264] (coalesced float4 loads)
  {
    const f32x4* xg = (const f32x4*)(x + (size_t)bid * 16384);
#pragma unroll
    for (int i = 0; i < 8; ++i) {
      int vi = i * 512 + tid;                 // float4 index, 4096 total
      f32x4 v = xg[vi];
      int row = vi >> 6;
      int col = (vi & 63) * 4;
      *(unsigned long long*)&lds[row * 264 + col] = pack4(v[0], v[1], v[2], v[3]);
    }
  }
  __syncthreads();   // B0: x staged

  // ---- Phase 2: qT = Wq @ xT, kT = Wk @ xT   (16x16x32 bf16)
  // C-output: lane holds qT[d = m*16 + lg*4 + e][tok = t*16 + lr]
  half4 qh[2][4], kh[2][4];    // [d-tile][tok-tile], A/B-frags for MFMA16
  {
    f32x4 qacc[2][4], kacc[2][4];
#pragma unroll
    for (int m = 0; m < 2; ++m)
#pragma unroll
      for (int t = 0; t < 4; ++t) {
        qacc[m][t] = z4;
        kacc[m][t] = z4;
      }
#pragma unroll
    for (int ks = 0; ks < 8; ++ks) {
      short8 xf[4];
#pragma unroll
      for (int t = 0; t < 4; ++t)
        xf[t] = *(const short8*)&lds[(t * 16 + lr) * 264 + ks * 32 + lg * 8];
      short8 wq[2], wk[2];
#pragma unroll
      for (int m = 0; m < 2; ++m) {
        wq[m] = *(const short8*)&qkv_wb[(w * 32 + m * 16 + lr) * 256 + ks * 32 + lg * 8];
        wk[m] = *(const short8*)&qkv_wb[(256 + w * 32 + m * 16 + lr) * 256 + ks * 32 + lg * 8];
      }
#pragma unroll
      for (int m = 0; m < 2; ++m)
#pragma unroll
        for (int t = 0; t < 4; ++t) {
          qacc[m][t] = MFMA32(wq[m], xf[t], qacc[m][t]);
          kacc[m][t] = MFMA32(wk[m], xf[t], kacc[m][t]);
        }
    }
#pragma unroll
    for (int m = 0; m < 2; ++m) {
      f32x4 bq = *(const f32x4*)&qkv_b[w * 32 + m * 16 + lg * 4];
      f32x4 bk = *(const f32x4*)&qkv_b[256 + w * 32 + m * 16 + lg * 4];
#pragma unroll
      for (int t = 0; t < 4; ++t)
#pragma unroll
        for (int e = 0; e < 4; ++e) {
          qh[m][t][e] = (_Float16)((qacc[m][t][e] + bq[e]) * SCALE);
          kh[m][t][e] = (_Float16)(kacc[m][t][e] + bk[e]);
        }
    }
  }

  // ---- Phase 3: S^T = k @ q^T (16x16x16 f16, K over d) + bias, softmax -> P^T
  // S^T lane: row tok_j = jt*16 + lg*4 + e, col tok_i = it*16 + lr.
  // Softmax over j for fixed i: 16 in-lane values + butterfly over lg (xor 16,32).
  half4 pb[4][4];    // [jt = PV k-step][it]
  {
    const float* rpe_h  = rpe + w * 4096;
    const float* mask_w = mask + (bid & 1023) * 4096;
#pragma unroll
    for (int it = 0; it < 4; ++it) {
      f32x4 sacc[4];
#pragma unroll
      for (int jt = 0; jt < 4; ++jt) {
        sacc[jt] = MFMA16(kh[0][jt], qh[0][it], z4);
        sacc[jt] = MFMA16(kh[1][jt], qh[1][it], sacc[jt]);
      }
      float mx = -3.0e38f;
#pragma unroll
      for (int jt = 0; jt < 4; ++jt) {
        f32x4 rp = *(const f32x4*)&rpe_h[(it * 16 + lr) * 64 + jt * 16 + lg * 4];
        f32x4 mk = *(const f32x4*)&mask_w[(it * 16 + lr) * 64 + jt * 16 + lg * 4];
#pragma unroll
        for (int e = 0; e < 4; ++e) {
          sacc[jt][e] = sacc[jt][e] + rp[e] + mk[e];
          mx = fmaxf(mx, sacc[jt][e]);
        }
      }
      mx = fmaxf(mx, __shfl_xor(mx, 16, 64));
      mx = fmaxf(mx, __shfl_xor(mx, 32, 64));
      float sum = 0.f;
#pragma unroll
      for (int jt = 0; jt < 4; ++jt)
#pragma unroll
        for (int e = 0; e < 4; ++e) {
          sacc[jt][e] = __expf(sacc[jt][e] - mx);
          sum += sacc[jt][e];
        }
      sum += __shfl_xor(sum, 16, 64);
      sum += __shfl_xor(sum, 32, 64);
      float inv = 1.0f / sum;
#pragma unroll
      for (int jt = 0; jt < 4; ++jt)
#pragma unroll
        for (int e = 0; e < 4; ++e)
          pb[jt][it][e] = (_Float16)(sacc[jt][e] * inv);
    }
  }

  // ---- Phase 4: v = x @ Wv^T (normal orientation; C-output IS the V^T A-frag)
  half4 vh[4][2];    // [tok-tile = PV k-step][d-tile]
  {
    f32x4 vacc[4][2];
#pragma unroll
    for (int t = 0; t < 4; ++t)
#pragma unroll
      for (int n = 0; n < 2; ++n)
        vacc[t][n] = z4;
#pragma unroll
    for (int ks = 0; ks < 8; ++ks) {
      short8 xf[4];
#pragma unroll
      for (int t = 0; t < 4; ++t)
        xf[t] = *(const short8*)&lds[(t * 16 + lr) * 264 + ks * 32 + lg * 8];
      short8 wv[2];
#pragma unroll
      for (int n = 0; n < 2; ++n)
        wv[n] = *(const short8*)&qkv_wb[(512 + w * 32 + n * 16 + lr) * 256 + ks * 32 + lg * 8];
#pragma unroll
      for (int t = 0; t < 4; ++t)
#pragma unroll
        for (int n = 0; n < 2; ++n)
          vacc[t][n] = MFMA32(xf[t], wv[n], vacc[t][n]);
    }
#pragma unroll
    for (int n = 0; n < 2; ++n) {
      float bv = qkv_b[512 + w * 32 + n * 16 + lr];
#pragma unroll
      for (int t = 0; t < 4; ++t)
#pragma unroll
        for (int e = 0; e < 4; ++e)
          vh[t][n][e] = (_Float16)(vacc[t][n][e] + bv);
    }
  }
  __syncthreads();   // B1: all waves done reading x (x-buf now dead)

  // ---- Phase 5: O^T = V^T @ P^T (16x16x16 f16, K over j, 4 k-steps)
  {
    f32x4 oacc[2][4];   // [dt][it]
#pragma unroll
    for (int dt = 0; dt < 2; ++dt)
#pragma unroll
      for (int it = 0; it < 4; ++it)
        oacc[dt][it] = z4;
#pragma unroll
    for (int kj = 0; kj < 4; ++kj)
#pragma unroll
      for (int dt = 0; dt < 2; ++dt)
#pragma unroll
        for (int it = 0; it < 4; ++it)
          oacc[dt][it] = MFMA16(vh[kj][dt], pb[kj][it], oacc[dt][it]);
    // O_all[tok][ch] bf16, row-major into dead x-buf; lane writes 4 consecutive ch
#pragma unroll
    for (int dt = 0; dt < 2; ++dt)
#pragma unroll
      for (int it = 0; it < 4; ++it)
        *(unsigned long long*)&lds[(it * 16 + lr) * 264 + w * 32 + dt * 16 + lg * 4]
            = pack4(oacc[dt][it][0], oacc[dt][it][1], oacc[dt][it][2], oacc[dt][it][3]);
  }
  __syncthreads();   // B2: O_all complete

  // ---- Phase 6: out^T = proj_w @ O_all^T + bias ; float4 global stores
  {
    f32x4 pacc[2][4];
#pragma unroll
    for (int m = 0; m < 2; ++m)
#pragma unroll
      for (int t = 0; t < 4; ++t)
        pacc[m][t] = z4;
#pragma unroll
    for (int ks = 0; ks < 8; ++ks) {
      short8 of[4];
#pragma unroll
      for (int t = 0; t < 4; ++t)
        of[t] = *(const short8*)&lds[(t * 16 + lr) * 264 + ks * 32 + lg * 8];
      short8 pw[2];
#pragma unroll
      for (int m = 0; m < 2; ++m)
        pw[m] = *(const short8*)&proj_wb[(w * 32 + m * 16 + lr) * 256 + ks * 32 + lg * 8];
#pragma unroll
      for (int m = 0; m < 2; ++m)
#pragma unroll
        for (int t = 0; t < 4; ++t)
          pacc[m][t] = MFMA32(pw[m], of[t], pacc[m][t]);
    }
    float* og = out + (size_t)bid * 16384;
#pragma unroll
    for (int m = 0; m < 2; ++m) {
      f32x4 bp = *(const f32x4*)&proj_b[w * 32 + m * 16 + lg * 4];
#pragma unroll
      for (int t = 0; t < 4; ++t) {
        f32x4 vv;
#pragma unroll
        for (int e = 0; e < 4; ++e) vv[e] = pacc[m][t][e] + bp[e];
        *(f32x4*)&og[(t * 16 + lr) * 256 + w * 32 + m * 16 + lg * 4] = vv;
      }
    }
  }
}

extern "C" void kernel_launch(void* const* d_in, const int* in_sizes, int n_in,
                              void* d_out, int out_size, void* d_ws, size_t ws_size,
                              hipStream_t stream) {
  (void)in_sizes; (void)n_in; (void)out_size; (void)ws_size;
  const float* x      = (const float*)d_in[0];
  const float* mask   = (const float*)d_in[1];
  const float* qkv_w  = (const float*)d_in[2];
  const float* qkv_b  = (const float*)d_in[3];
  const float* proj_w = (const float*)d_in[4];
  const float* proj_b = (const float*)d_in[5];
  const float* rpb    = (const float*)d_in[6];
  const int*   rel    = (const int*)d_in[7];

  unsigned short* qkv_wb  = (unsigned short*)d_ws;                       // 393216 B
  unsigned short* proj_wb = (unsigned short*)((char*)d_ws + 393216);     // 131072 B
  float*          rpe     = (float*)((char*)d_ws + 524288);              // 131072 B
  float*          out     = (float*)d_out;

  prep_kernel<<<dim3(1152), dim3(256), 0, stream>>>(qkv_w, proj_w, rpb, rel,
                                                    qkv_wb, proj_wb, rpe);
  win_attn_kernel<<<dim3(4096), dim3(512), 0, stream>>>(x, mask, qkv_wb, qkv_b,
                                                        proj_wb, proj_b, rpe, out);
}

// Round 4
// 510.848 us; speedup vs baseline: 1.7006x; 1.7006x over previous
//
#include <hip/hip_runtime.h>

#define SCALE 0.17677669529663687f

typedef __attribute__((ext_vector_type(8))) short short8;
typedef __attribute__((ext_vector_type(4))) float f32x4;
typedef __attribute__((ext_vector_type(4))) _Float16 half4;

__device__ __forceinline__ f32x4 MFMA32(short8 a, short8 b, f32x4 c) {
  return __builtin_amdgcn_mfma_f32_16x16x32_bf16(a, b, c, 0, 0, 0);
}

__device__ __forceinline__ f32x4 MFMA16(half4 a, half4 b, f32x4 c) {
  return __builtin_amdgcn_mfma_f32_16x16x16f16(a, b, c, 0, 0, 0);
}

__device__ __forceinline__ unsigned short f2bf(float f) {
  unsigned u = __float_as_uint(f);
  u += 0x7fffu + ((u >> 16) & 1u);
  return (unsigned short)(u >> 16);
}

__device__ __forceinline__ unsigned long long pack4(float a, float b, float c, float d) {
  unsigned lo = (unsigned)f2bf(a) | ((unsigned)f2bf(b) << 16);
  unsigned hi = (unsigned)f2bf(c) | ((unsigned)f2bf(d) << 16);
  return (unsigned long long)lo | ((unsigned long long)hi << 32);
}

// ---- Prologue: weights fp32->bf16 + rpe gather, one kernel.
__global__ void prep_kernel(const float* __restrict__ qkv_w,
                            const float* __restrict__ proj_w,
                            const float* __restrict__ table,
                            const int* __restrict__ rel,
                            unsigned short* __restrict__ qkv_wb,
                            unsigned short* __restrict__ proj_wb,
                            float* __restrict__ rpe) {
  int idx = blockIdx.x * 256 + threadIdx.x;   // 1152 * 256 = 294912 exact
  if (idx < 196608) {
    qkv_wb[idx] = f2bf(qkv_w[idx]);
  } else if (idx < 262144) {
    int p = idx - 196608;
    proj_wb[p] = f2bf(proj_w[p]);
  } else {
    int t = idx - 262144;                     // 0..32767
    int h = t >> 12, ij = t & 4095;
    rpe[t] = table[rel[ij] * 8 + h];
  }
}

// ---- Main fused kernel: one block per window, 8 waves = 8 heads.
// All attention intermediates (q,k,v,S,P,O) live in REGISTERS via transposed
// MFMA chaining; LDS holds only x (bf16, [64][264]) reused later for O_all.
// launch_bounds min-waves = 2: VGPR cap 256 — R3's (512,4) forced a 64-VGPR
// clamp -> ~2.4 GB/dispatch scratch spill traffic. Natural allocation here
// is ~120-170 VGPR; spills are far worse than lower occupancy.
__global__ __launch_bounds__(512, 2)
void win_attn_kernel(const float* __restrict__ x,
                     const float* __restrict__ mask,
                     const unsigned short* __restrict__ qkv_wb,
                     const float* __restrict__ qkv_b,
                     const unsigned short* __restrict__ proj_wb,
                     const float* __restrict__ proj_b,
                     const float* __restrict__ rpe,
                     float* __restrict__ out) {
  __shared__ unsigned short lds[64 * 264];
  const int bid  = blockIdx.x;
  const int tid  = threadIdx.x;
  const int w    = tid >> 6;     // wave = head
  const int lane = tid & 63;
  const int lr   = lane & 15;
  const int lg   = lane >> 4;
  const f32x4 z4 = {0.f, 0.f, 0.f, 0.f};

  // ---- Phase 1: stage x -> LDS bf16 [64][264] (coalesced float4 loads)
  {
    const f32x4* xg = (const f32x4*)(x + (size_t)bid * 16384);
#pragma unroll
    for (int i = 0; i < 8; ++i) {
      int vi = i * 512 + tid;                 // float4 index, 4096 total
      f32x4 v = xg[vi];
      int row = vi >> 6;
      int col = (vi & 63) * 4;
      *(unsigned long long*)&lds[row * 264 + col] = pack4(v[0], v[1], v[2], v[3]);
    }
  }
  __syncthreads();   // B0: x staged

  // ---- Phase 2: qT = Wq @ xT, kT = Wk @ xT   (16x16x32 bf16)
  // C-output: lane holds qT[d = m*16 + lg*4 + e][tok = t*16 + lr]
  half4 qh[2][4], kh[2][4];    // [d-tile][tok-tile], A/B-frags for MFMA16
  {
    f32x4 qacc[2][4], kacc[2][4];
#pragma unroll
    for (int m = 0; m < 2; ++m)
#pragma unroll
      for (int t = 0; t < 4; ++t) {
        qacc[m][t] = z4;
        kacc[m][t] = z4;
      }
#pragma unroll
    for (int ks = 0; ks < 8; ++ks) {
      short8 xf[4];
#pragma unroll
      for (int t = 0; t < 4; ++t)
        xf[t] = *(const short8*)&lds[(t * 16 + lr) * 264 + ks * 32 + lg * 8];
      short8 wq[2], wk[2];
#pragma unroll
      for (int m = 0; m < 2; ++m) {
        wq[m] = *(const short8*)&qkv_wb[(w * 32 + m * 16 + lr) * 256 + ks * 32 + lg * 8];
        wk[m] = *(const short8*)&qkv_wb[(256 + w * 32 + m * 16 + lr) * 256 + ks * 32 + lg * 8];
      }
#pragma unroll
      for (int m = 0; m < 2; ++m)
#pragma unroll
        for (int t = 0; t < 4; ++t) {
          qacc[m][t] = MFMA32(wq[m], xf[t], qacc[m][t]);
          kacc[m][t] = MFMA32(wk[m], xf[t], kacc[m][t]);
        }
    }
#pragma unroll
    for (int m = 0; m < 2; ++m) {
      f32x4 bq = *(const f32x4*)&qkv_b[w * 32 + m * 16 + lg * 4];
      f32x4 bk = *(const f32x4*)&qkv_b[256 + w * 32 + m * 16 + lg * 4];
#pragma unroll
      for (int t = 0; t < 4; ++t)
#pragma unroll
        for (int e = 0; e < 4; ++e) {
          qh[m][t][e] = (_Float16)((qacc[m][t][e] + bq[e]) * SCALE);
          kh[m][t][e] = (_Float16)(kacc[m][t][e] + bk[e]);
        }
    }
  }

  // ---- Phase 3: S^T = k @ q^T (16x16x16 f16, K over d) + bias, softmax -> P^T
  // S^T lane: row tok_j = jt*16 + lg*4 + e, col tok_i = it*16 + lr.
  // Softmax over j for fixed i: 16 in-lane values + butterfly over lg (xor 16,32).
  half4 pb[4][4];    // [jt = PV k-step][it]
  {
    const float* rpe_h  = rpe + w * 4096;
    const float* mask_w = mask + (bid & 1023) * 4096;
#pragma unroll
    for (int it = 0; it < 4; ++it) {
      f32x4 sacc[4];
#pragma unroll
      for (int jt = 0; jt < 4; ++jt) {
        sacc[jt] = MFMA16(kh[0][jt], qh[0][it], z4);
        sacc[jt] = MFMA16(kh[1][jt], qh[1][it], sacc[jt]);
      }
      float mx = -3.0e38f;
#pragma unroll
      for (int jt = 0; jt < 4; ++jt) {
        f32x4 rp = *(const f32x4*)&rpe_h[(it * 16 + lr) * 64 + jt * 16 + lg * 4];
        f32x4 mk = *(const f32x4*)&mask_w[(it * 16 + lr) * 64 + jt * 16 + lg * 4];
#pragma unroll
        for (int e = 0; e < 4; ++e) {
          sacc[jt][e] = sacc[jt][e] + rp[e] + mk[e];
          mx = fmaxf(mx, sacc[jt][e]);
        }
      }
      mx = fmaxf(mx, __shfl_xor(mx, 16, 64));
      mx = fmaxf(mx, __shfl_xor(mx, 32, 64));
      float sum = 0.f;
#pragma unroll
      for (int jt = 0; jt < 4; ++jt)
#pragma unroll
        for (int e = 0; e < 4; ++e) {
          sacc[jt][e] = __expf(sacc[jt][e] - mx);
          sum += sacc[jt][e];
        }
      sum += __shfl_xor(sum, 16, 64);
      sum += __shfl_xor(sum, 32, 64);
      float inv = 1.0f / sum;
#pragma unroll
      for (int jt = 0; jt < 4; ++jt)
#pragma unroll
        for (int e = 0; e < 4; ++e)
          pb[jt][it][e] = (_Float16)(sacc[jt][e] * inv);
    }
  }

  // ---- Phase 4: v = x @ Wv^T (normal orientation; C-output IS the V^T A-frag)
  half4 vh[4][2];    // [tok-tile = PV k-step][d-tile]
  {
    f32x4 vacc[4][2];
#pragma unroll
    for (int t = 0; t < 4; ++t)
#pragma unroll
      for (int n = 0; n < 2; ++n)
        vacc[t][n] = z4;
#pragma unroll
    for (int ks = 0; ks < 8; ++ks) {
      short8 xf[4];
#pragma unroll
      for (int t = 0; t < 4; ++t)
        xf[t] = *(const short8*)&lds[(t * 16 + lr) * 264 + ks * 32 + lg * 8];
      short8 wv[2];
#pragma unroll
      for (int n = 0; n < 2; ++n)
        wv[n] = *(const short8*)&qkv_wb[(512 + w * 32 + n * 16 + lr) * 256 + ks * 32 + lg * 8];
#pragma unroll
      for (int t = 0; t < 4; ++t)
#pragma unroll
        for (int n = 0; n < 2; ++n)
          vacc[t][n] = MFMA32(xf[t], wv[n], vacc[t][n]);
    }
#pragma unroll
    for (int n = 0; n < 2; ++n) {
      float bv = qkv_b[512 + w * 32 + n * 16 + lr];
#pragma unroll
      for (int t = 0; t < 4; ++t)
#pragma unroll
        for (int e = 0; e < 4; ++e)
          vh[t][n][e] = (_Float16)(vacc[t][n][e] + bv);
    }
  }
  __syncthreads();   // B1: all waves done reading x (x-buf now dead)

  // ---- Phase 5: O^T = V^T @ P^T (16x16x16 f16, K over j, 4 k-steps)
  {
    f32x4 oacc[2][4];   // [dt][it]
#pragma unroll
    for (int dt = 0; dt < 2; ++dt)
#pragma unroll
      for (int it = 0; it < 4; ++it)
        oacc[dt][it] = z4;
#pragma unroll
    for (int kj = 0; kj < 4; ++kj)
#pragma unroll
      for (int dt = 0; dt < 2; ++dt)
#pragma unroll
        for (int it = 0; it < 4; ++it)
          oacc[dt][it] = MFMA16(vh[kj][dt], pb[kj][it], oacc[dt][it]);
    // O_all[tok][ch] bf16, row-major into dead x-buf; lane writes 4 consecutive ch
#pragma unroll
    for (int dt = 0; dt < 2; ++dt)
#pragma unroll
      for (int it = 0; it < 4; ++it)
        *(unsigned long long*)&lds[(it * 16 + lr) * 264 + w * 32 + dt * 16 + lg * 4]
            = pack4(oacc[dt][it][0], oacc[dt][it][1], oacc[dt][it][2], oacc[dt][it][3]);
  }
  __syncthreads();   // B2: O_all complete

  // ---- Phase 6: out^T = proj_w @ O_all^T + bias ; float4 global stores
  {
    f32x4 pacc[2][4];
#pragma unroll
    for (int m = 0; m < 2; ++m)
#pragma unroll
      for (int t = 0; t < 4; ++t)
        pacc[m][t] = z4;
#pragma unroll
    for (int ks = 0; ks < 8; ++ks) {
      short8 of[4];
#pragma unroll
      for (int t = 0; t < 4; ++t)
        of[t] = *(const short8*)&lds[(t * 16 + lr) * 264 + ks * 32 + lg * 8];
      short8 pw[2];
#pragma unroll
      for (int m = 0; m < 2; ++m)
        pw[m] = *(const short8*)&proj_wb[(w * 32 + m * 16 + lr) * 256 + ks * 32 + lg * 8];
#pragma unroll
      for (int m = 0; m < 2; ++m)
#pragma unroll
        for (int t = 0; t < 4; ++t)
          pacc[m][t] = MFMA32(pw[m], of[t], pacc[m][t]);
    }
    float* og = out + (size_t)bid * 16384;
#pragma unroll
    for (int m = 0; m < 2; ++m) {
      f32x4 bp = *(const f32x4*)&proj_b[w * 32 + m * 16 + lg * 4];
#pragma unroll
      for (int t = 0; t < 4; ++t) {
        f32x4 vv;
#pragma unroll
        for (int e = 0; e < 4; ++e) vv[e] = pacc[m][t][e] + bp[e];
        *(f32x4*)&og[(t * 16 + lr) * 256 + w * 32 + m * 16 + lg * 4] = vv;
      }
    }
  }
}

extern "C" void kernel_launch(void* const* d_in, const int* in_sizes, int n_in,
                              void* d_out, int out_size, void* d_ws, size_t ws_size,
                              hipStream_t stream) {
  (void)in_sizes; (void)n_in; (void)out_size; (void)ws_size;
  const float* x      = (const float*)d_in[0];
  const float* mask   = (const float*)d_in[1];
  const float* qkv_w  = (const float*)d_in[2];
  const float* qkv_b  = (const float*)d_in[3];
  const float* proj_w = (const float*)d_in[4];
  const float* proj_b = (const float*)d_in[5];
  const float* rpb    = (const float*)d_in[6];
  const int*   rel    = (const int*)d_in[7];

  unsigned short* qkv_wb  = (unsigned short*)d_ws;                       // 393216 B
  unsigned short* proj_wb = (unsigned short*)((char*)d_ws + 393216);     // 131072 B
  float*          rpe     = (float*)((char*)d_ws + 524288);              // 131072 B
  float*          out     = (float*)d_out;

  prep_kernel<<<dim3(1152), dim3(256), 0, stream>>>(qkv_w, proj_w, rpb, rel,
                                                    qkv_wb, proj_wb, rpe);
  win_attn_kernel<<<dim3(4096), dim3(512), 0, stream>>>(x, mask, qkv_wb, qkv_b,
                                                        proj_wb, proj_b, rpe, out);
}

// Round 5
// 435.035 us; speedup vs baseline: 1.9969x; 1.1743x over previous
//
#include <hip/hip_runtime.h>

#define SCALE 0.17677669529663687f

typedef __attribute__((ext_vector_type(8))) short short8;
typedef __attribute__((ext_vector_type(4))) float f32x4;
typedef __attribute__((ext_vector_type(4))) _Float16 half4;

__device__ __forceinline__ f32x4 MFMA32(short8 a, short8 b, f32x4 c) {
  return __builtin_amdgcn_mfma_f32_16x16x32_bf16(a, b, c, 0, 0, 0);
}

__device__ __forceinline__ f32x4 MFMA16(half4 a, half4 b, f32x4 c) {
  return __builtin_amdgcn_mfma_f32_16x16x16f16(a, b, c, 0, 0, 0);
}

__device__ __forceinline__ unsigned short f2bf(float f) {
  unsigned u = __float_as_uint(f);
  u += 0x7fffu + ((u >> 16) & 1u);
  return (unsigned short)(u >> 16);
}

__device__ __forceinline__ unsigned long long pack4(float a, float b, float c, float d) {
  unsigned lo = (unsigned)f2bf(a) | ((unsigned)f2bf(b) << 16);
  unsigned hi = (unsigned)f2bf(c) | ((unsigned)f2bf(d) << 16);
  return (unsigned long long)lo | ((unsigned long long)hi << 32);
}

// ---- Prologue: weights fp32->bf16 (q-rows pre-scaled by SCALE), rpe gather,
// scaled qkv bias copy. 1155*256 = 295680 threads exact.
__global__ void prep_kernel(const float* __restrict__ qkv_w,
                            const float* __restrict__ proj_w,
                            const float* __restrict__ table,
                            const int* __restrict__ rel,
                            const float* __restrict__ qkv_b,
                            unsigned short* __restrict__ qkv_wb,
                            unsigned short* __restrict__ proj_wb,
                            float* __restrict__ rpe,
                            float* __restrict__ qkv_bs) {
  int idx = blockIdx.x * 256 + threadIdx.x;
  if (idx < 196608) {
    float v = qkv_w[idx];
    if (idx < 65536) v *= SCALE;            // q rows: fold softmax scale
    qkv_wb[idx] = f2bf(v);
  } else if (idx < 262144) {
    int p = idx - 196608;
    proj_wb[p] = f2bf(proj_w[p]);
  } else if (idx < 294912) {
    int t = idx - 262144;                   // 0..32767
    int h = t >> 12, ij = t & 4095;
    rpe[t] = table[rel[ij] * 8 + h];
  } else {
    int i = idx - 294912;                   // 0..767
    qkv_bs[i] = qkv_b[i] * (i < 256 ? SCALE : 1.0f);
  }
}

// ---- Main fused kernel: one block per window, 8 waves = 8 heads.
// Intermediates in registers via transposed MFMA chaining. LDS: x bf16
// [64][264] (reused for O_all) + shared mask f32 [64][68].
// (512,2): VGPR cap 256; natural alloc 128 -> 2 blocks/CU. (512,4) spilled.
__global__ __launch_bounds__(512, 2)
void win_attn_kernel(const float* __restrict__ x,
                     const float* __restrict__ mask,
                     const unsigned short* __restrict__ qkv_wb,
                     const float* __restrict__ qkv_bs,
                     const unsigned short* __restrict__ proj_wb,
                     const float* __restrict__ proj_b,
                     const float* __restrict__ rpe,
                     float* __restrict__ out) {
  __shared__ __align__(16) unsigned char smem[51200];
  unsigned short* xb = (unsigned short*)smem;        // [64][264] bf16
  float*          mk = (float*)(smem + 33792);       // [64][68]  f32
  const int bid  = blockIdx.x;
  const int tid  = threadIdx.x;
  const int w    = tid >> 6;     // wave = head
  const int lane = tid & 63;
  const int lr   = lane & 15;
  const int lg   = lane >> 4;

  // ---- Phase 1: stage x -> LDS bf16; mask -> LDS f32 (all coalesced)
  {
    const f32x4* xg = (const f32x4*)(x + (size_t)bid * 16384);
#pragma unroll
    for (int i = 0; i < 8; ++i) {
      int vi = i * 512 + tid;                 // 4096 float4
      f32x4 v = xg[vi];
      int row = vi >> 6;
      int col = (vi & 63) * 4;
      *(unsigned long long*)&xb[row * 264 + col] = pack4(v[0], v[1], v[2], v[3]);
    }
    const f32x4* mg = (const f32x4*)(mask + (size_t)(bid & 1023) * 4096);
#pragma unroll
    for (int i = 0; i < 2; ++i) {
      int vi = i * 512 + tid;                 // 1024 float4
      f32x4 v = mg[vi];
      int row = vi >> 4;
      int col = (vi & 15) * 4;
      *(f32x4*)&mk[row * 68 + col] = v;
    }
  }
  __syncthreads();   // B0

  // ---- Phase 2: qT = Wq' @ xT, kT = Wk @ xT  (bias pre-loaded into acc)
  half4 qh[2][4], kh[2][4];    // [d-tile][tok-tile]
  {
    f32x4 qacc[2][4], kacc[2][4];
#pragma unroll
    for (int m = 0; m < 2; ++m) {
      f32x4 bq = *(const f32x4*)&qkv_bs[w * 32 + m * 16 + lg * 4];
      f32x4 bk = *(const f32x4*)&qkv_bs[256 + w * 32 + m * 16 + lg * 4];
#pragma unroll
      for (int t = 0; t < 4; ++t) {
        qacc[m][t] = bq;
        kacc[m][t] = bk;
      }
    }
#pragma unroll
    for (int ks = 0; ks < 8; ++ks) {
      short8 xf[4];
#pragma unroll
      for (int t = 0; t < 4; ++t)
        xf[t] = *(const short8*)&xb[(t * 16 + lr) * 264 + ks * 32 + lg * 8];
      short8 wq[2], wk[2];
#pragma unroll
      for (int m = 0; m < 2; ++m) {
        wq[m] = *(const short8*)&qkv_wb[(w * 32 + m * 16 + lr) * 256 + ks * 32 + lg * 8];
        wk[m] = *(const short8*)&qkv_wb[(256 + w * 32 + m * 16 + lr) * 256 + ks * 32 + lg * 8];
      }
#pragma unroll
      for (int m = 0; m < 2; ++m)
#pragma unroll
        for (int t = 0; t < 4; ++t) {
          qacc[m][t] = MFMA32(wq[m], xf[t], qacc[m][t]);
          kacc[m][t] = MFMA32(wk[m], xf[t], kacc[m][t]);
        }
    }
#pragma unroll
    for (int m = 0; m < 2; ++m)
#pragma unroll
      for (int t = 0; t < 4; ++t)
#pragma unroll
        for (int e = 0; e < 4; ++e) {
          qh[m][t][e] = (_Float16)qacc[m][t][e];
          kh[m][t][e] = (_Float16)kacc[m][t][e];
        }
  }

  // ---- Phase 3: S^T = k @ q^T with C-init = rpe + mask; softmax -> P^T
  // S^T lane: row tok_j = jt*16 + lg*4 + e, col tok_i = it*16 + lr.
  half4 pb[4][4];    // [jt = PV k-step][it]
  {
    const float* rpe_h = rpe + w * 4096;
#pragma unroll
    for (int it = 0; it < 4; ++it) {
      f32x4 binit[4];
#pragma unroll
      for (int jt = 0; jt < 4; ++jt)
        binit[jt] = *(const f32x4*)&rpe_h[(it * 16 + lr) * 64 + jt * 16 + lg * 4];
#pragma unroll
      for (int jt = 0; jt < 4; ++jt) {
        f32x4 mv = *(const f32x4*)&mk[(it * 16 + lr) * 68 + jt * 16 + lg * 4];
#pragma unroll
        for (int e = 0; e < 4; ++e) binit[jt][e] += mv[e];
      }
      f32x4 sacc[4];
#pragma unroll
      for (int jt = 0; jt < 4; ++jt) {
        sacc[jt] = MFMA16(kh[0][jt], qh[0][it], binit[jt]);
        sacc[jt] = MFMA16(kh[1][jt], qh[1][it], sacc[jt]);
      }
      float mx = -3.0e38f;
#pragma unroll
      for (int jt = 0; jt < 4; ++jt)
#pragma unroll
        for (int e = 0; e < 4; ++e)
          mx = fmaxf(mx, sacc[jt][e]);
      mx = fmaxf(mx, __shfl_xor(mx, 16, 64));
      mx = fmaxf(mx, __shfl_xor(mx, 32, 64));
      float sum = 0.f;
#pragma unroll
      for (int jt = 0; jt < 4; ++jt)
#pragma unroll
        for (int e = 0; e < 4; ++e) {
          sacc[jt][e] = __expf(sacc[jt][e] - mx);
          sum += sacc[jt][e];
        }
      sum += __shfl_xor(sum, 16, 64);
      sum += __shfl_xor(sum, 32, 64);
      float inv = 1.0f / sum;
#pragma unroll
      for (int jt = 0; jt < 4; ++jt)
#pragma unroll
        for (int e = 0; e < 4; ++e)
          pb[jt][it][e] = (_Float16)(sacc[jt][e] * inv);
    }
  }

  // ---- Phase 4: v = x @ Wv^T (C-output IS the V^T A-frag); bias in acc-init
  half4 vh[4][2];    // [tok-tile = PV k-step][d-tile]
  {
    f32x4 vacc[4][2];
#pragma unroll
    for (int n = 0; n < 2; ++n) {
      float bv = qkv_bs[512 + w * 32 + n * 16 + lr];
#pragma unroll
      for (int t = 0; t < 4; ++t) {
        f32x4 iv = {bv, bv, bv, bv};
        vacc[t][n] = iv;
      }
    }
#pragma unroll
    for (int ks = 0; ks < 8; ++ks) {
      short8 xf[4];
#pragma unroll
      for (int t = 0; t < 4; ++t)
        xf[t] = *(const short8*)&xb[(t * 16 + lr) * 264 + ks * 32 + lg * 8];
      short8 wv[2];
#pragma unroll
      for (int n = 0; n < 2; ++n)
        wv[n] = *(const short8*)&qkv_wb[(512 + w * 32 + n * 16 + lr) * 256 + ks * 32 + lg * 8];
#pragma unroll
      for (int t = 0; t < 4; ++t)
#pragma unroll
        for (int n = 0; n < 2; ++n)
          vacc[t][n] = MFMA32(xf[t], wv[n], vacc[t][n]);
    }
#pragma unroll
    for (int t = 0; t < 4; ++t)
#pragma unroll
      for (int n = 0; n < 2; ++n)
#pragma unroll
        for (int e = 0; e < 4; ++e)
          vh[t][n][e] = (_Float16)vacc[t][n][e];
  }
  __syncthreads();   // B1: x-buf dead

  // ---- Phase 5: O^T = V^T @ P^T
  {
    f32x4 oacc[2][4];   // [dt][it]
    const f32x4 z4 = {0.f, 0.f, 0.f, 0.f};
#pragma unroll
    for (int dt = 0; dt < 2; ++dt)
#pragma unroll
      for (int it = 0; it < 4; ++it)
        oacc[dt][it] = z4;
#pragma unroll
    for (int kj = 0; kj < 4; ++kj)
#pragma unroll
      for (int dt = 0; dt < 2; ++dt)
#pragma unroll
        for (int it = 0; it < 4; ++it)
          oacc[dt][it] = MFMA16(vh[kj][dt], pb[kj][it], oacc[dt][it]);
#pragma unroll
    for (int dt = 0; dt < 2; ++dt)
#pragma unroll
      for (int it = 0; it < 4; ++it)
        *(unsigned long long*)&xb[(it * 16 + lr) * 264 + w * 32 + dt * 16 + lg * 4]
            = pack4(oacc[dt][it][0], oacc[dt][it][1], oacc[dt][it][2], oacc[dt][it][3]);
  }
  __syncthreads();   // B2: O_all complete

  // ---- Phase 6: out^T = proj_w @ O_all^T; bias in acc-init; float4 stores
  {
    f32x4 pacc[2][4];
#pragma unroll
    for (int m = 0; m < 2; ++m) {
      f32x4 bp = *(const f32x4*)&proj_b[w * 32 + m * 16 + lg * 4];
#pragma unroll
      for (int t = 0; t < 4; ++t)
        pacc[m][t] = bp;
    }
#pragma unroll
    for (int ks = 0; ks < 8; ++ks) {
      short8 of[4];
#pragma unroll
      for (int t = 0; t < 4; ++t)
        of[t] = *(const short8*)&xb[(t * 16 + lr) * 264 + ks * 32 + lg * 8];
      short8 pw[2];
#pragma unroll
      for (int m = 0; m < 2; ++m)
        pw[m] = *(const short8*)&proj_wb[(w * 32 + m * 16 + lr) * 256 + ks * 32 + lg * 8];
#pragma unroll
      for (int m = 0; m < 2; ++m)
#pragma unroll
        for (int t = 0; t < 4; ++t)
          pacc[m][t] = MFMA32(pw[m], of[t], pacc[m][t]);
    }
    float* og = out + (size_t)bid * 16384;
#pragma unroll
    for (int m = 0; m < 2; ++m)
#pragma unroll
      for (int t = 0; t < 4; ++t)
        *(f32x4*)&og[(t * 16 + lr) * 256 + w * 32 + m * 16 + lg * 4] = pacc[m][t];
  }
}

extern "C" void kernel_launch(void* const* d_in, const int* in_sizes, int n_in,
                              void* d_out, int out_size, void* d_ws, size_t ws_size,
                              hipStream_t stream) {
  (void)in_sizes; (void)n_in; (void)out_size; (void)ws_size;
  const float* x      = (const float*)d_in[0];
  const float* mask   = (const float*)d_in[1];
  const float* qkv_w  = (const float*)d_in[2];
  const float* qkv_b  = (const float*)d_in[3];
  const float* proj_w = (const float*)d_in[4];
  const float* proj_b = (const float*)d_in[5];
  const float* rpb    = (const float*)d_in[6];
  const int*   rel    = (const int*)d_in[7];

  unsigned short* qkv_wb  = (unsigned short*)d_ws;                       // 393216 B
  unsigned short* proj_wb = (unsigned short*)((char*)d_ws + 393216);     // 131072 B
  float*          rpe     = (float*)((char*)d_ws + 524288);              // 131072 B
  float*          qkv_bs  = (float*)((char*)d_ws + 655360);              // 3072 B
  float*          out     = (float*)d_out;

  prep_kernel<<<dim3(1155), dim3(256), 0, stream>>>(qkv_w, proj_w, rpb, rel, qkv_b,
                                                    qkv_wb, proj_wb, rpe, qkv_bs);
  win_attn_kernel<<<dim3(4096), dim3(512), 0, stream>>>(x, mask, qkv_wb, qkv_bs,
                                                        proj_wb, proj_b, rpe, out);
}